// Round 2
// 1770.309 us; speedup vs baseline: 1.0051x; 1.0051x over previous
//
#include <hip/hip_runtime.h>
#include <cstdint>
#include <cstddef>

#define F       256
#define NCLASS  47
#define CSR_W   64

#define NSRC0 1081344
#define NDST0 67584
#define NE0   1013760
#define NSRC1 67584
#define NDST1 6144
#define NE1   61440
#define NSRC2 6144
#define NDST2 1024
#define NE2   5120

// ---- workspace layout (bytes) ----
#define O_CNTSRC0 ((size_t)0)
#define O_CURDST0 (O_CNTSRC0 + (size_t)NSRC0 * 4)
#define O_CNTSRC1 (O_CURDST0 + (size_t)NDST0 * 4)
#define O_CURDST1 (O_CNTSRC1 + (size_t)NSRC1 * 4)
#define O_CNTSRC2 (O_CURDST1 + (size_t)NDST1 * 4)
#define O_CURDST2 (O_CNTSRC2 + (size_t)NSRC2 * 4)
#define ZBYTES    (O_CURDST2 + (size_t)NDST2 * 4)           // ~4.9 MB zeroed each call
#define O_CSR0    ZBYTES
#define O_CSR1    (O_CSR0 + (size_t)NDST0 * CSR_W * 4)
#define O_CSR2    (O_CSR1 + (size_t)NDST1 * CSR_W * 4)
#define O_AGG0    (O_CSR2 + (size_t)NDST2 * CSR_W * 4)
#define O_AGG1    (O_AGG0 + (size_t)NDST0 * F * 4)
#define O_AGG2    (O_AGG1 + (size_t)NDST1 * F * 4)
// total = O_AGG2 + 1024*256*4 = 100,601,856 bytes (~96 MB)

// ---------------------------------------------------------------------------
// Fused edge-parallel CSR build for all 3 layers. Edge ranges are exact
// multiples of 256 (NE0=256*3960, NE1=256*240, NE2=256*20) so every block is
// range-uniform: no divergence. One launch instead of three lets the small
// builds overlap the big one's tail.
// ---------------------------------------------------------------------------
__global__ __launch_bounds__(256) void build_csr3(
    const int* __restrict__ src0, const int* __restrict__ dst0,
    const int* __restrict__ src1, const int* __restrict__ dst1,
    const int* __restrict__ src2, const int* __restrict__ dst2,
    unsigned* __restrict__ cnt0, unsigned* __restrict__ cur0, int* __restrict__ csr0,
    unsigned* __restrict__ cnt1, unsigned* __restrict__ cur1, int* __restrict__ csr1,
    unsigned* __restrict__ cnt2, unsigned* __restrict__ cur2, int* __restrict__ csr2) {
  int e = blockIdx.x * 256 + threadIdx.x;
  const int* src; const int* dst;
  unsigned* cnt; unsigned* cur; int* csr;
  if (e < NE0) {
    src = src0; dst = dst0; cnt = cnt0; cur = cur0; csr = csr0;
  } else if (e < NE0 + NE1) {
    e -= NE0;
    src = src1; dst = dst1; cnt = cnt1; cur = cur1; csr = csr1;
  } else {
    e -= NE0 + NE1;
    src = src2; dst = dst2; cnt = cnt2; cur = cur2; csr = csr2;
  }
  int s = src[e];
  int d = dst[e];
  atomicAdd(&cnt[s], 1u);
  unsigned pos = atomicAdd(&cur[d], 1u);
  if (pos < CSR_W) csr[(size_t)d * CSR_W + pos] = s;
}

// ---------------------------------------------------------------------------
// Wave-per-dst aggregation, 4-deep software pipeline:
// acc = deg_in^-1/2 * sum_e deg_out^-1/2 * feat[src_e]
// Edge ids + src scales prefetched into lanes, broadcast with __shfl.
// Main loop processes 4 edges per iteration into 4 independent accumulators
// so 4 x 1KB loads stay in flight per wave (was 1 -> latency-bound risk).
// ---------------------------------------------------------------------------
__global__ __launch_bounds__(256) void gather_kernel(
    const float* __restrict__ feat, const int* __restrict__ csr,
    const unsigned* __restrict__ cnt_src, const unsigned* __restrict__ cur_dst,
    float* __restrict__ out, int nDst) {
  int gid  = blockIdx.x * blockDim.x + threadIdx.x;
  int d    = gid >> 6;
  int lane = threadIdx.x & 63;
  if (d >= nDst) return;

  unsigned deg_full = cur_dst[d];
  int deg = (int)(deg_full < CSR_W ? deg_full : CSR_W);
  float scale_in = rsqrtf((float)(deg_full > 0u ? deg_full : 1u));

  int   s_l  = 0;
  float so_l = 0.f;
  if (lane < deg) {
    s_l = csr[(size_t)d * CSR_W + lane];
    unsigned c = cnt_src[s_l];
    so_l = rsqrtf((float)(c > 0u ? c : 1u));
  }

  const float* fb = feat + lane * 4;   // per-lane base; row offset added per edge

  float4 a0 = make_float4(0.f, 0.f, 0.f, 0.f);
  float4 a1 = a0, a2 = a0, a3 = a0;

  int j = 0;
  int deg4 = deg & ~3;
  for (; j < deg4; j += 4) {
    int   sA = __shfl(s_l, j + 0);
    int   sB = __shfl(s_l, j + 1);
    int   sC = __shfl(s_l, j + 2);
    int   sD = __shfl(s_l, j + 3);
    float cA = __shfl(so_l, j + 0);
    float cB = __shfl(so_l, j + 1);
    float cC = __shfl(so_l, j + 2);
    float cD = __shfl(so_l, j + 3);
    float4 vA = *(const float4*)(fb + (size_t)sA * F);
    float4 vB = *(const float4*)(fb + (size_t)sB * F);
    float4 vC = *(const float4*)(fb + (size_t)sC * F);
    float4 vD = *(const float4*)(fb + (size_t)sD * F);
    a0.x = fmaf(cA, vA.x, a0.x); a0.y = fmaf(cA, vA.y, a0.y);
    a0.z = fmaf(cA, vA.z, a0.z); a0.w = fmaf(cA, vA.w, a0.w);
    a1.x = fmaf(cB, vB.x, a1.x); a1.y = fmaf(cB, vB.y, a1.y);
    a1.z = fmaf(cB, vB.z, a1.z); a1.w = fmaf(cB, vB.w, a1.w);
    a2.x = fmaf(cC, vC.x, a2.x); a2.y = fmaf(cC, vC.y, a2.y);
    a2.z = fmaf(cC, vC.z, a2.z); a2.w = fmaf(cC, vC.w, a2.w);
    a3.x = fmaf(cD, vD.x, a3.x); a3.y = fmaf(cD, vD.y, a3.y);
    a3.z = fmaf(cD, vD.z, a3.z); a3.w = fmaf(cD, vD.w, a3.w);
  }
  for (; j < deg; ++j) {
    int   s  = __shfl(s_l, j);
    float so = __shfl(so_l, j);
    float4 v = *(const float4*)(fb + (size_t)s * F);
    a0.x = fmaf(so, v.x, a0.x); a0.y = fmaf(so, v.y, a0.y);
    a0.z = fmaf(so, v.z, a0.z); a0.w = fmaf(so, v.w, a0.w);
  }

  float4 acc;
  acc.x = ((a0.x + a1.x) + (a2.x + a3.x)) * scale_in;
  acc.y = ((a0.y + a1.y) + (a2.y + a3.y)) * scale_in;
  acc.z = ((a0.z + a1.z) + (a2.z + a3.z)) * scale_in;
  acc.w = ((a0.w + a1.w) + (a2.w + a3.w)) * scale_in;
  *(float4*)(out + (size_t)d * F + lane * 4) = acc;
}

// ---------------------------------------------------------------------------
// In-place row transform: A[M,256] = act(A @ W[256,256] + b).
// Block owns 32 full rows (full col width => in-place is race-free).
// BK=32; A staged transposed in LDS (pad 36 keeps float4 alignment, <=4-way
// store conflict); thread computes 8 rows x 4 cols = 32 FMA per 3 b128 reads
// (2 of the 3 are wave-uniform broadcasts => cheap).
// ---------------------------------------------------------------------------
#define TBM 32
#define TBK 32
#define APAD 36

__global__ __launch_bounds__(256) void transform_kernel(
    float* __restrict__ A, const float* __restrict__ W,
    const float* __restrict__ bias, int do_relu) {
  __shared__ float As[TBK * APAD];   // [kk][row]
  __shared__ float Ws[TBK * F];      // [kk][n]
  const int t    = threadIdx.x;
  const int row0 = blockIdx.x * TBM;
  const int c4   = (t & 63) * 4;     // 4 output cols (lane-contiguous b128 on Ws)
  const int r8   = (t >> 6) * 8;     // 8 output rows (broadcast b128 on As)
  const int row_a = t >> 3;          // A staging: row
  const int kq    = (t & 7) * 4;     // A staging: 4 consecutive k

  float acc[8][4] = {};

  for (int k0 = 0; k0 < F; k0 += TBK) {
    float4 av = *(const float4*)(A + (size_t)(row0 + row_a) * F + k0 + kq);
    float4 wv[8];
#pragma unroll
    for (int i = 0; i < 8; ++i) {
      int idx = i * 256 + t;         // float4 index into 32x256 tile
      int kk  = idx >> 6;
      int n4  = (idx & 63) * 4;
      wv[i] = *(const float4*)(W + (size_t)(k0 + kk) * F + n4);
    }
    if (k0) __syncthreads();
    As[(kq + 0) * APAD + row_a] = av.x;
    As[(kq + 1) * APAD + row_a] = av.y;
    As[(kq + 2) * APAD + row_a] = av.z;
    As[(kq + 3) * APAD + row_a] = av.w;
#pragma unroll
    for (int i = 0; i < 8; ++i) {
      int idx = i * 256 + t;
      int kk  = idx >> 6;
      int n4  = (idx & 63) * 4;
      *(float4*)(Ws + kk * F + n4) = wv[i];
    }
    __syncthreads();
#pragma unroll
    for (int kk = 0; kk < TBK; ++kk) {
      float4 w  = *(const float4*)(Ws + kk * F + c4);
      float4 a0 = *(const float4*)(As + kk * APAD + r8);
      float4 a1 = *(const float4*)(As + kk * APAD + r8 + 4);
      float ar[8] = {a0.x, a0.y, a0.z, a0.w, a1.x, a1.y, a1.z, a1.w};
      float wr[4] = {w.x, w.y, w.z, w.w};
#pragma unroll
      for (int r = 0; r < 8; ++r)
#pragma unroll
        for (int c = 0; c < 4; ++c)
          acc[r][c] = fmaf(ar[r], wr[c], acc[r][c]);
    }
  }

  float4 bv = *(const float4*)(bias + c4);
#pragma unroll
  for (int r = 0; r < 8; ++r) {
    float4 o;
    o.x = acc[r][0] + bv.x;
    o.y = acc[r][1] + bv.y;
    o.z = acc[r][2] + bv.z;
    o.w = acc[r][3] + bv.w;
    if (do_relu) {
      o.x = fmaxf(o.x, 0.f); o.y = fmaxf(o.y, 0.f);
      o.z = fmaxf(o.z, 0.f); o.w = fmaxf(o.w, 0.f);
    }
    *(float4*)(A + (size_t)(row0 + r8 + r) * F + c4) = o;
  }
}

// ---------------------------------------------------------------------------
// Final 256->47 layer (25 MFLOP): thread per (row, col<47), no activation.
// ---------------------------------------------------------------------------
__global__ __launch_bounds__(256) void final_kernel(
    const float* __restrict__ A, const float* __restrict__ W2,
    const float* __restrict__ b2, float* __restrict__ out) {
  int idx = blockIdx.x * blockDim.x + threadIdx.x;
  int row = idx >> 6;
  int col = idx & 63;
  if (row >= NDST2 || col >= NCLASS) return;
  const float* a = A + (size_t)row * F;
  float acc = 0.f;
#pragma unroll 8
  for (int k = 0; k < F; ++k) acc = fmaf(a[k], W2[k * NCLASS + col], acc);
  out[row * NCLASS + col] = acc + b2[col];
}

extern "C" void kernel_launch(void* const* d_in, const int* in_sizes, int n_in,
                              void* d_out, int out_size, void* d_ws, size_t ws_size,
                              hipStream_t stream) {
  const float* x    = (const float*)d_in[0];
  const int*   src0 = (const int*)d_in[1];
  const int*   dst0 = (const int*)d_in[2];
  const int*   src1 = (const int*)d_in[3];
  const int*   dst1 = (const int*)d_in[4];
  const int*   src2 = (const int*)d_in[5];
  const int*   dst2 = (const int*)d_in[6];
  const float* W0   = (const float*)d_in[7];
  const float* b0   = (const float*)d_in[8];
  const float* W1   = (const float*)d_in[9];
  const float* b1   = (const float*)d_in[10];
  const float* W2   = (const float*)d_in[11];
  const float* b2   = (const float*)d_in[12];
  float* out = (float*)d_out;
  char*  ws  = (char*)d_ws;

  unsigned* cnt_src0 = (unsigned*)(ws + O_CNTSRC0);
  unsigned* cur_dst0 = (unsigned*)(ws + O_CURDST0);
  unsigned* cnt_src1 = (unsigned*)(ws + O_CNTSRC1);
  unsigned* cur_dst1 = (unsigned*)(ws + O_CURDST1);
  unsigned* cnt_src2 = (unsigned*)(ws + O_CNTSRC2);
  unsigned* cur_dst2 = (unsigned*)(ws + O_CURDST2);
  int*   csr0 = (int*)(ws + O_CSR0);
  int*   csr1 = (int*)(ws + O_CSR1);
  int*   csr2 = (int*)(ws + O_CSR2);
  float* agg0 = (float*)(ws + O_AGG0);
  float* agg1 = (float*)(ws + O_AGG1);
  float* agg2 = (float*)(ws + O_AGG2);

  // ws is re-poisoned to 0xAA before every timed launch: re-zero the count zone.
  hipMemsetAsync(ws, 0, ZBYTES, stream);

  // one fused CSR-build launch for all three layers
  build_csr3<<<(NE0 + NE1 + NE2) / 256, 256, 0, stream>>>(
      src0, dst0, src1, dst1, src2, dst2,
      cnt_src0, cur_dst0, csr0,
      cnt_src1, cur_dst1, csr1,
      cnt_src2, cur_dst2, csr2);

  // layer 0: aggregate x -> agg0, transform in-place (+ReLU)
  gather_kernel<<<NDST0 / 4, 256, 0, stream>>>(x, csr0, cnt_src0, cur_dst0, agg0, NDST0);
  transform_kernel<<<NDST0 / TBM, 256, 0, stream>>>(agg0, W0, b0, 1);

  // layer 1
  gather_kernel<<<NDST1 / 4, 256, 0, stream>>>(agg0, csr1, cnt_src1, cur_dst1, agg1, NDST1);
  transform_kernel<<<NDST1 / TBM, 256, 0, stream>>>(agg1, W1, b1, 1);

  // layer 2: aggregate then 256->47 projection straight into d_out
  gather_kernel<<<NDST2 / 4, 256, 0, stream>>>(agg1, csr2, cnt_src2, cur_dst2, agg2, NDST2);
  final_kernel<<<(NDST2 * 64) / 256, 256, 0, stream>>>(agg2, W2, b2, out);
}